// Round 1
// 157.044 us; speedup vs baseline: 1.6208x; 1.6208x over previous
//
#include <hip/hip_runtime.h>

#define NV 40962
#define NF 81920
#define BSZ 8
#define CIN 32
#define COUT 64
#define BC 256   // BSZ*CIN

typedef unsigned short u16;
typedef float  f32x4  __attribute__((ext_vector_type(4)));
typedef __bf16 bf16x8 __attribute__((ext_vector_type(8)));
typedef short  s16x8  __attribute__((ext_vector_type(8)));

__device__ __forceinline__ float bf2f(u16 h) {
    return __uint_as_float(((unsigned int)h) << 16);
}
__device__ __forceinline__ u16 f2bf(float f) {
    unsigned int u = __float_as_uint(f);
    unsigned int r = (u + 0x7fffu + ((u >> 16) & 1u)) >> 16;
    return (u16)r;
}

// ---------------- Kernel A: transpose input (256 x NV f32) -> xt (NV x 256 bf16)
__global__ __launch_bounds__(256) void k_transpose(const float* __restrict__ in,
                                                   u16* __restrict__ xt) {
    __shared__ float tile[32][33];   // [bc_local][v_local]
    int c0 = blockIdx.x * 32;   // v-dim tile start
    int r0 = blockIdx.y * 32;   // bc-dim tile start
    int tx = threadIdx.x & 31;
    int ty = threadIdx.x >> 5;  // 0..7
    #pragma unroll
    for (int i = 0; i < 32; i += 8) {
        int cc = c0 + tx;
        float v = 0.f;
        if (cc < NV) v = in[(size_t)(r0 + ty + i) * NV + cc];
        tile[ty + i][tx] = v;
    }
    __syncthreads();
    int t = threadIdx.x;
    #pragma unroll
    for (int e = t; e < 512; e += 256) {
        int vl = e >> 4;          // 0..31 (v_local)
        int p  = e & 15;          // channel pair
        int v  = c0 + vl;
        if (v < NV) {
            ushort2 val;
            val.x = f2bf(tile[p * 2][vl]);
            val.y = f2bf(tile[p * 2 + 1][vl]);
            *(ushort2*)&xt[(size_t)v * BC + r0 + p * 2] = val;
        }
    }
}

// ---------------- Kernel B: per-face EW/NS-folded gradient features (bf16 out)
__global__ __launch_bounds__(256) void k_faces(const u16* __restrict__ xt,
                                               const int* __restrict__ Gc,
                                               const float* __restrict__ Gv,
                                               const float* __restrict__ EW,
                                               const float* __restrict__ NS,
                                               u16* __restrict__ gfew,
                                               u16* __restrict__ gfns) {
    int t  = threadIdx.x;
    int f  = blockIdx.x * 2 + (t >> 7);   // 2 faces per block
    int c2 = t & 127;                     // channel pair 0..127
    float a0ew = 0.f, a1ew = 0.f, a0ns = 0.f, a1ns = 0.f;
    #pragma unroll
    for (int d = 0; d < 3; ++d) {
        int base = 3 * (d * NF + f);
        float g0 = 0.f, g1 = 0.f;
        #pragma unroll
        for (int j = 0; j < 3; ++j) {
            int   col = Gc[base + j];
            float val = Gv[base + j];
            ushort2 xv = *(const ushort2*)&xt[(size_t)col * BC + c2 * 2];
            g0 += val * bf2f(xv.x);
            g1 += val * bf2f(xv.y);
        }
        float ew = EW[f * 3 + d], ns = NS[f * 3 + d];
        a0ew += ew * g0;  a1ew += ew * g1;
        a0ns += ns * g0;  a1ns += ns * g1;
    }
    ushort2 o;
    o.x = f2bf(a0ew); o.y = f2bf(a1ew);
    *(ushort2*)&gfew[(size_t)f * BC + c2 * 2] = o;
    o.x = f2bf(a0ns); o.y = f2bf(a1ns);
    *(ushort2*)&gfns[(size_t)f * BC + c2 * 2] = o;
}

// ---------------- Kernel C: per 8-vertex tile, ALL batches+channels in one block.
// Gathers read full 512B rows (no 8x batch re-fetch); epilogue GEMM on MFMA with
// bf16 hi/lo split (f32-equivalent precision).
#define VT 8
#define FROW 136            // shorts per feat row: 128 ck + 8 pad (272 B, bank-uniform)
#define FBP  (16 * FROW)    // one batch-pair tile: 16 rows

__global__ __launch_bounds__(256) void k_vertices(const u16* __restrict__ xt,
                                                  const int* __restrict__ Lc,
                                                  const float* __restrict__ Lv,
                                                  const int* __restrict__ Fc,
                                                  const float* __restrict__ Fv,
                                                  const u16* __restrict__ gfew,
                                                  const u16* __restrict__ gfns,
                                                  const float* __restrict__ coeffs,
                                                  float* __restrict__ out) {
    __shared__ short fhi[4 * FBP];   // 17408 shorts = 34.8 KB total with flo
    __shared__ short flo[4 * FBP];
    int t = threadIdx.x;

    // ---- bijective XCD-aware swizzle (nwg = 5121, not %8==0 -> m204 form)
    const int nwg = (NV + VT - 1) / VT;
    const int q = nwg >> 3, r = nwg & 7;
    int orig = blockIdx.x;
    int xcd = orig & 7, lid = orig >> 3;
    int swz = (xcd < r ? xcd * (q + 1) : r * (q + 1) + (xcd - r) * q) + lid;
    int v0 = swz * VT;

    // ---- B fragments (coeffs 128x64 f32, L1/L2-resident): hi/lo bf16 split
    int w  = t >> 6;          // wave id -> o-tile (w*16)
    int l  = t & 63;
    int lr = l & 15;          // o within tile / A-row
    int lq = l >> 4;          // k-octet select
    bf16x8 Bhi[4], Blo[4];
    #pragma unroll
    for (int ks = 0; ks < 4; ++ks) {
        s16x8 hb, lb;
        #pragma unroll
        for (int e = 0; e < 8; ++e) {
            int k = ks * 32 + lq * 8 + e;
            float c = coeffs[k * 64 + w * 16 + lr];
            u16 h = f2bf(c);
            hb[e] = (short)h;
            lb[e] = (short)f2bf(c - bf2f(h));
        }
        Bhi[ks] = __builtin_bit_cast(bf16x8, hb);
        Blo[ks] = __builtin_bit_cast(bf16x8, lb);
    }

    // ---- phase 1: gather features. thread = (channel-pair p, vertex-half vh).
    // 128 threads x ushort2 = full 512B row per gather.
    int p   = t & 127;        // bc-pair: b = p>>4, c2 = p&15
    int vh  = t >> 7;         // 0..1
    int b   = p >> 4;
    int c2  = p & 15;
    int bc0 = p * 2;          // = b*32 + c2*2
    int bp  = b >> 1;
    int rbase = (b & 1) * 8;
    #pragma unroll
    for (int vi = 0; vi < 4; ++vi) {
        int vloc = vh * 4 + vi;
        int v = v0 + vloc;
        float id0 = 0.f, id1 = 0.f, lap0 = 0.f, lap1 = 0.f;
        float ew0 = 0.f, ew1 = 0.f, ns0 = 0.f, ns1 = 0.f;
        if (v < NV) {
            ushort2 xv = *(const ushort2*)&xt[(size_t)v * BC + bc0];
            id0 = bf2f(xv.x);  id1 = bf2f(xv.y);
            #pragma unroll
            for (int j = 0; j < 7; ++j) {
                int   col = Lc[7 * v + j];
                float val = Lv[7 * v + j];
                ushort2 lv2 = *(const ushort2*)&xt[(size_t)col * BC + bc0];
                lap0 += val * bf2f(lv2.x);
                lap1 += val * bf2f(lv2.y);
            }
            #pragma unroll
            for (int j = 0; j < 6; ++j) {
                int   col = Fc[6 * v + j];
                float val = Fv[6 * v + j];
                ushort2 e2 = *(const ushort2*)&gfew[(size_t)col * BC + bc0];
                ushort2 n2 = *(const ushort2*)&gfns[(size_t)col * BC + bc0];
                ew0 += val * bf2f(e2.x);  ew1 += val * bf2f(e2.y);
                ns0 += val * bf2f(n2.x);  ns1 += val * bf2f(n2.y);
            }
        }
        float fv[8] = {id0, lap0, ew0, ns0, id1, lap1, ew1, ns1};
        s16x8 hb, lb;
        #pragma unroll
        for (int e = 0; e < 8; ++e) {
            u16 h = f2bf(fv[e]);
            hb[e] = (short)h;
            lb[e] = (short)f2bf(fv[e] - bf2f(h));
        }
        int idx = bp * FBP + (rbase + vloc) * FROW + c2 * 8;
        *(s16x8*)&fhi[idx] = hb;
        *(s16x8*)&flo[idx] = lb;
    }
    __syncthreads();

    // ---- phase 2: per wave one 16-o tile; loop 4 batch-pairs; K=128 in 4 steps.
    // A rows = (b&1)*8 + v. 3 MFMA per step (hh, lh, hl) ~= f32 product.
    #pragma unroll
    for (int bp2 = 0; bp2 < 4; ++bp2) {
        f32x4 acc = {0.f, 0.f, 0.f, 0.f};
        #pragma unroll
        for (int ks = 0; ks < 4; ++ks) {
            int aidx = bp2 * FBP + lr * FROW + ks * 32 + lq * 8;
            bf16x8 Ahi = *(const bf16x8*)&fhi[aidx];
            bf16x8 Alo = *(const bf16x8*)&flo[aidx];
            acc = __builtin_amdgcn_mfma_f32_16x16x32_bf16(Ahi, Bhi[ks], acc, 0, 0, 0);
            acc = __builtin_amdgcn_mfma_f32_16x16x32_bf16(Alo, Bhi[ks], acc, 0, 0, 0);
            acc = __builtin_amdgcn_mfma_f32_16x16x32_bf16(Ahi, Blo[ks], acc, 0, 0, 0);
        }
        // C layout: col = lane&15 (o), rows = lq*4 + j
        int r0 = lq * 4;
        int bb = bp2 * 2 + (r0 >> 3);
        int vbase = v0 + (r0 & 7);
        int o = w * 16 + lr;
        size_t off = ((size_t)(bb * 64 + o)) * NV + vbase;
        if (v0 + VT <= NV) {
            // off is only guaranteed 8B-aligned (NV%4==2): two float2 stores
            *(float2*)&out[off]     = make_float2(acc.x, acc.y);
            *(float2*)&out[off + 2] = make_float2(acc.z, acc.w);
        } else {
            #pragma unroll
            for (int j = 0; j < 4; ++j)
                if (vbase + j < NV) out[off + j] = acc[j];
        }
    }
}

extern "C" void kernel_launch(void* const* d_in, const int* in_sizes, int n_in,
                              void* d_out, int out_size, void* d_ws, size_t ws_size,
                              hipStream_t stream) {
    (void)in_sizes; (void)n_in; (void)out_size; (void)ws_size;
    const float* input = (const float*)d_in[0];
    const int*   Gc = (const int*)d_in[2];
    const float* Gv = (const float*)d_in[3];
    const int*   Lc = (const int*)d_in[5];
    const float* Lv = (const float*)d_in[6];
    const int*   Fc = (const int*)d_in[8];
    const float* Fv = (const float*)d_in[9];
    const float* EW = (const float*)d_in[10];
    const float* NS = (const float*)d_in[11];
    const float* coeffs = (const float*)d_in[12];
    float* out = (float*)d_out;

    u16* ws   = (u16*)d_ws;
    u16* xt   = ws;                                   // NV*256 bf16
    u16* gfew = ws + (size_t)NV * BC;                 // NF*256 bf16
    u16* gfns = gfew + (size_t)NF * BC;               // NF*256 bf16

    dim3 gA((NV + 31) / 32, BC / 32);
    k_transpose<<<gA, 256, 0, stream>>>(input, xt);

    k_faces<<<dim3(NF / 2), 256, 0, stream>>>(xt, Gc, Gv, EW, NS, gfew, gfns);

    k_vertices<<<dim3((NV + VT - 1) / VT), 256, 0, stream>>>(
        xt, Lc, Lv, Fc, Fv, gfew, gfns, coeffs, out);
}